// Round 11
// baseline (252.831 us; speedup 1.0000x reference)
//
#include <hip/hip_runtime.h>
#include <math.h>

// Problem constants
#define LSEQ   4096
#define DHALF  256
#define NSTATE 8
#define NCHUNK 256           // scan chunks
#define CLEN   16            // chunk length (NCHUNK*CLEN = 4096)

typedef __attribute__((ext_vector_type(8))) _Float16 half8;   // MFMA f16 A/B frag
typedef __attribute__((ext_vector_type(4))) _Float16 half4v;
typedef __attribute__((ext_vector_type(4))) float f32x4;

__device__ __forceinline__ float silu_f(float v)     { return v / (1.0f + __expf(-v)); }
__device__ __forceinline__ float softplus_f(float v) { return v > 20.0f ? v : log1pf(__expf(v)); }

// async global->LDS, 16B per lane; LDS dest = wave-uniform base + lane*16
__device__ __forceinline__ void gload16(const void* g, void* l) {
    __builtin_amdgcn_global_load_lds((const __attribute__((address_space(1))) void*)g,
                                     (__attribute__((address_space(3))) void*)l, 16, 0, 0);
}

// ============================================================================
// fp32 -> fp16 cast (3 tensors) + Wdt transpose, one launch.
// ============================================================================
__global__ __launch_bounds__(256)
void k_cast_all(const float* __restrict__ s0, _Float16* __restrict__ d0,
                const float* __restrict__ s1, _Float16* __restrict__ d1,
                const float* __restrict__ s2, _Float16* __restrict__ d2,
                const float* __restrict__ wdt, float* __restrict__ wtT)
{
    int i = blockIdx.x * 256 + threadIdx.x;
    if (i >= 1310720) {                       // seg3: transpose Wdt
        int j = i - 1310720;                  // 0..8191
        int d = j >> 5, k = j & 31;
        wtT[k * 256 + d] = wdt[j];
        return;
    }
    const float* src; _Float16* dst; int off;
    if (i < 1048576)      { src = s0; dst = d0; off = i; }
    else if (i < 1179648) { src = s1; dst = d1; off = i - 1048576; }
    else                  { src = s2; dst = d2; off = i - 1179648; }
    float4 v = ((const float4*)src)[off];
    half4v h;
    h.x = (_Float16)v.x; h.y = (_Float16)v.y; h.z = (_Float16)v.z; h.w = (_Float16)v.w;
    ((half4v*)dst)[off] = h;
}

// ============================================================================
// MFMA bt-GEMM core (C = A * B^T), fp16 single-product (fp32 accumulate).
// 128(M) x 64(N) tile / block, 4 waves each 64x32 via 4x2 16x16x32 MFMAs.
// BK=64. LDS rows 128B; 16B chunks XOR-swizzled by (row&7) so fragment
// ds_read_b128 is 2-way bank-aliased (free). Swizzle applied on the per-lane
// GLOBAL source chunk (LDS dst stays uniform base + lane*16).
// M0_/N0_ passed in for XCD-swizzled block ids: same-M0 blocks share bid%8
// -> same XCD -> A-slab fetched ~once per XCD.
// (r9-proven geometry: r10's 128x128/64x128 variants dropped to 2 blk/CU
// and REGRESSED 235->251 us — keep 128x64.)
// ============================================================================
#define GEMM_CORE_F16(K_, M0_, N0_)                                                     \
    const int t = threadIdx.x;                                                          \
    const int wv = t >> 6, lane = t & 63;                                               \
    const int wm = (wv & 1) * 64, wn = (wv >> 1) * 32;                                  \
    const int lm = lane & 15, q = lane >> 4;                                            \
    const int M0 = (M0_), N0 = (N0_);                                                   \
    const int lr = lane >> 3;                  /* row within 8-row group */             \
    const int cc = (lane & 7) ^ lr;            /* swizzled source chunk  */             \
    const size_t gA = (size_t)(M0 + wv * 32 + lr) * K_ + cc * 8;                        \
    const size_t gB = (size_t)(N0 + wv * 16 + lr) * K_ + cc * 8;                        \
    f32x4 acc[4][2] = {};                                                               \
    for (int kb = 0; kb < K_; kb += 64) {                                               \
        __syncthreads();                                                                \
        gload16(Af + gA + kb,               &sA[(wv * 32 +  0) * 64]);                  \
        gload16(Af + gA + (size_t)8  * K_ + kb, &sA[(wv * 32 +  8) * 64]);              \
        gload16(Af + gA + (size_t)16 * K_ + kb, &sA[(wv * 32 + 16) * 64]);              \
        gload16(Af + gA + (size_t)24 * K_ + kb, &sA[(wv * 32 + 24) * 64]);              \
        gload16(Bf + gB + kb,               &sB[(wv * 16 +  0) * 64]);                  \
        gload16(Bf + gB + (size_t)8  * K_ + kb, &sB[(wv * 16 +  8) * 64]);              \
        __syncthreads();                                                                \
        _Pragma("unroll")                                                               \
        for (int kk = 0; kk < 2; ++kk) {                                                \
            const int cpos = (((kk << 2) + q) ^ (lm & 7)) * 8;                          \
            half8 a[4], b[2];                                                           \
            _Pragma("unroll")                                                           \
            for (int i = 0; i < 4; ++i)                                                 \
                a[i] = *(const half8*)&sA[(wm + i * 16 + lm) * 64 + cpos];              \
            _Pragma("unroll")                                                           \
            for (int j = 0; j < 2; ++j)                                                 \
                b[j] = *(const half8*)&sB[(wn + j * 16 + lm) * 64 + cpos];              \
            _Pragma("unroll")                                                           \
            for (int i = 0; i < 4; ++i)                                                 \
                _Pragma("unroll")                                                       \
                for (int j = 0; j < 2; ++j)                                             \
                    acc[i][j] = __builtin_amdgcn_mfma_f32_16x16x32_f16(a[i], b[j], acc[i][j], 0, 0, 0); \
        }                                                                               \
    }

// in_proj: M=8192 (b,l), N=1024 (e), K=512. Epilogue scatter folds direction
// split + reverse; x-regions -> fp32 (scan path), z-regions -> fp16 (safe,
// non-recurrent; r10 confirmed numerics). 1D grid 1024, XCD-swizzled.
__global__ __launch_bounds__(256)
void k_in_proj_mfma(const _Float16* __restrict__ Af, const _Float16* __restrict__ Bf,
                    float* __restrict__ x_t, _Float16* __restrict__ z_t)
{
    __shared__ _Float16 sA[128 * 64], sB[64 * 64];
    GEMM_CORE_F16(512, (int)(blockIdx.x & 63) * 128, (int)(blockIdx.x >> 6) * 64)
    const int region = N0 >> 8;               // 0..3 uniform per block
    const int eobase = (N0 & 255) + wn;
    if ((region & 1) == 0) {                  // x-regions -> fp32
#pragma unroll
        for (int i = 0; i < 4; ++i) {
#pragma unroll
            for (int r = 0; r < 4; ++r) {
                int m = M0 + wm + i * 16 + q * 4 + r;
                int b = m >> 12, l = m & 4095;
                size_t rowoff = (region < 2)
                    ? ((size_t)b * 4096 + l) * 256
                    : ((size_t)(b + 2) * 4096 + (4095 - l)) * 256;
#pragma unroll
                for (int j = 0; j < 2; ++j)
                    x_t[rowoff + eobase + j * 16 + lm] = acc[i][j][r];
            }
        }
    } else {                                  // z-regions -> fp16
#pragma unroll
        for (int i = 0; i < 4; ++i) {
#pragma unroll
            for (int r = 0; r < 4; ++r) {
                int m = M0 + wm + i * 16 + q * 4 + r;
                int b = m >> 12, l = m & 4095;
                size_t rowoff = (region < 2)
                    ? ((size_t)b * 4096 + l) * 256
                    : ((size_t)(b + 2) * 4096 + (4095 - l)) * 256;
#pragma unroll
                for (int j = 0; j < 2; ++j)
                    z_t[rowoff + eobase + j * 16 + lm] = (_Float16)acc[i][j][r];
            }
        }
    }
}

// out_proj: M=8192 (b,l), N=512 (o), K=1024. 1D grid 512; by=bid&63, bx=bid>>6.
__global__ __launch_bounds__(256)
void k_out_proj_mfma(const _Float16* __restrict__ Af, const _Float16* __restrict__ Bf,
                     float* __restrict__ out)
{
    __shared__ _Float16 sA[128 * 64], sB[64 * 64];
    GEMM_CORE_F16(1024, (int)(blockIdx.x & 63) * 128, (int)(blockIdx.x >> 6) * 64)
#pragma unroll
    for (int i = 0; i < 4; ++i) {
#pragma unroll
        for (int r = 0; r < 4; ++r) {
            size_t m = (size_t)(M0 + wm + i * 16 + q * 4 + r);
#pragma unroll
            for (int j = 0; j < 2; ++j)
                out[m * 512 + N0 + wn + j * 16 + lm] = acc[i][j][r];
        }
    }
}

// ============================================================================
// conv_x: dilated (8) causal depthwise conv + SiLU, fp32 float4 (scan path).
// ============================================================================
__global__ __launch_bounds__(256)
void k_conv_x4(const float* __restrict__ x_t, const float* __restrict__ w,
               float* __restrict__ u_t)
{
    int idx = blockIdx.x * 256 + threadIdx.x;
    int b = idx >> 18, rem = idx & 262143;
    int l = rem >> 6, d0 = (rem & 63) * 4;
    const float* base = x_t + (size_t)b * 4096 * 256 + d0;
    float4 wv0 = *(const float4*)(w + (d0 + 0) * 4);
    float4 wv1 = *(const float4*)(w + (d0 + 1) * 4);
    float4 wv2 = *(const float4*)(w + (d0 + 2) * 4);
    float4 wv3 = *(const float4*)(w + (d0 + 3) * 4);
    float4 tp = *(const float4*)(base + (size_t)l * 256);
    float4 a = make_float4(wv0.w * tp.x, wv1.w * tp.y, wv2.w * tp.z, wv3.w * tp.w);
    if (l >= 8) {
        tp = *(const float4*)(base + (size_t)(l - 8) * 256);
        a.x += wv0.z * tp.x; a.y += wv1.z * tp.y; a.z += wv2.z * tp.z; a.w += wv3.z * tp.w;
    }
    if (l >= 16) {
        tp = *(const float4*)(base + (size_t)(l - 16) * 256);
        a.x += wv0.y * tp.x; a.y += wv1.y * tp.y; a.z += wv2.y * tp.z; a.w += wv3.y * tp.w;
    }
    if (l >= 24) {
        tp = *(const float4*)(base + (size_t)(l - 24) * 256);
        a.x += wv0.x * tp.x; a.y += wv1.x * tp.y; a.z += wv2.x * tp.z; a.w += wv3.x * tp.w;
    }
    float4 o = make_float4(silu_f(a.x), silu_f(a.y), silu_f(a.z), silu_f(a.w));
    *(float4*)(u_t + ((size_t)b * 4096 + l) * 256 + d0) = o;
}

// ============================================================================
// conv_z: dilation-1 causal conv + SiLU, fp16 in/out (non-recurrent path).
// Direction un-reversal folded in. yb: [2][4096][1024] fp16
// ============================================================================
__global__ __launch_bounds__(256)
void k_conv_z8(const _Float16* __restrict__ z_t, const float* __restrict__ w,
               _Float16* __restrict__ yb)
{
    int idx = blockIdx.x * 256 + threadIdx.x;
    int b = idx >> 17, rem = idx & 131071;
    int l = rem >> 5, d0 = (rem & 31) * 8;
    const _Float16* base = z_t + (size_t)b * 4096 * 256 + d0;
    float acc[8];
    {
        half8 v = *(const half8*)(base + (size_t)l * 256);
#pragma unroll
        for (int k = 0; k < 8; ++k) acc[k] = w[(d0 + k) * 4 + 3] * (float)v[k];
    }
    if (l >= 1) {
        half8 v = *(const half8*)(base + (size_t)(l - 1) * 256);
#pragma unroll
        for (int k = 0; k < 8; ++k) acc[k] += w[(d0 + k) * 4 + 2] * (float)v[k];
    }
    if (l >= 2) {
        half8 v = *(const half8*)(base + (size_t)(l - 2) * 256);
#pragma unroll
        for (int k = 0; k < 8; ++k) acc[k] += w[(d0 + k) * 4 + 1] * (float)v[k];
    }
    if (l >= 3) {
        half8 v = *(const half8*)(base + (size_t)(l - 3) * 256);
#pragma unroll
        for (int k = 0; k < 8; ++k) acc[k] += w[(d0 + k) * 4 + 0] * (float)v[k];
    }
    size_t oidx = (b < 2) ? ((size_t)b * 4096 + l) * 1024 + 256 + d0
                          : ((size_t)(b - 2) * 4096 + (4095 - l)) * 1024 + 768 + d0;
    half8 o;
#pragma unroll
    for (int k = 0; k < 8; ++k) o[k] = (_Float16)silu_f(acc[k]);
    *(half8*)(yb + oidx) = o;
}

// ============================================================================
// x_proj: xdbl[m][e] = sum_d u_t[m][d] * Wx[e][d];  M=16384, N=48, K=256
// 512 blocks of 32 rows.
// ============================================================================
__global__ __launch_bounds__(256)
void k_xproj(const float* __restrict__ U, const float* __restrict__ W,
             float* __restrict__ xdbl)
{
    __shared__ float Xs[32][260];
    __shared__ float Ws[48][68];
    const int t  = threadIdx.x;
    const int m0 = blockIdx.x * 32;
#pragma unroll
    for (int it = 0; it < 8; ++it) {       // 32x256 = 2048 float4
        int idx = t + 256 * it;
        int row = idx >> 6, c = (idx & 63) * 4;
        *(float4*)&Xs[row][c] = *(const float4*)(U + (size_t)(m0 + row) * 256 + c);
    }
    const int r  = t >> 3;                 // 0..31
    const int j0 = (t & 7) * 6;            // 0..42
    float acc[6] = {};
    for (int kb = 0; kb < 256; kb += 64) {
        __syncthreads();
#pragma unroll
        for (int it = 0; it < 3; ++it) {   // 48x64 = 768 float4
            int idx = t + 256 * it;
            int wr = idx >> 4, wc = (idx & 15) * 4;
            *(float4*)&Ws[wr][wc] = *(const float4*)(W + (size_t)wr * 256 + kb + wc);
        }
        __syncthreads();
#pragma unroll
        for (int k4 = 0; k4 < 16; ++k4) {
            float4 x = *(const float4*)&Xs[r][kb + k4 * 4];
#pragma unroll
            for (int jj = 0; jj < 6; ++jj) {
                float4 wv = *(const float4*)&Ws[j0 + jj][k4 * 4];
                acc[jj] = fmaf(x.x, wv.x, acc[jj]);
                acc[jj] = fmaf(x.y, wv.y, acc[jj]);
                acc[jj] = fmaf(x.z, wv.z, acc[jj]);
                acc[jj] = fmaf(x.w, wv.w, acc[jj]);
            }
        }
    }
    float* dst = xdbl + (size_t)(m0 + r) * 48 + j0;
#pragma unroll
    for (int jj = 0; jj < 6; ++jj) dst[jj] = acc[jj];
}

// ============================================================================
// dt_proj + softplus. Thread = channel d; W from TRANSPOSED WT[32][256]
// (coalesced wave-load). 1024 blocks x 16 m-rows.
// ============================================================================
__global__ __launch_bounds__(256)
void k_dtproj(const float* __restrict__ xdbl, const float* __restrict__ WT,
              const float* __restrict__ bdt, float* __restrict__ delta_t)
{
    __shared__ float Xs[16][32];
    const int t  = threadIdx.x;            // d = t
    const int m0 = blockIdx.x * 16;
    if (t < 128) {                         // 16x32 floats = 128 float4
        int r = t >> 3, c = (t & 7) * 4;
        *(float4*)&Xs[r][c] = *(const float4*)(xdbl + (size_t)(m0 + r) * 48 + c);
    }
    float w[32];
#pragma unroll
    for (int k = 0; k < 32; ++k) w[k] = WT[k * 256 + t];
    const float bias = bdt[t];
    __syncthreads();
#pragma unroll
    for (int m = 0; m < 16; ++m) {
        const float4* xr = (const float4*)&Xs[m][0];
        float acc = bias;
#pragma unroll
        for (int j = 0; j < 8; ++j) {
            float4 xv = xr[j];
            acc = fmaf(xv.x, w[4*j+0], acc);
            acc = fmaf(xv.y, w[4*j+1], acc);
            acc = fmaf(xv.z, w[4*j+2], acc);
            acc = fmaf(xv.w, w[4*j+3], acc);
        }
        delta_t[(size_t)(m0 + m) * 256 + t] = softplus_f(acc);
    }
}

// ============================================================================
// Selective scan, chunked (NCHUNK=256 chunks x CLEN=16 steps). All fp32.
// Staging guards: 128 writers into [8][16] — in bounds.
// ============================================================================
__global__ __launch_bounds__(256)
void k_scan1(const float* __restrict__ delta_t, const float* __restrict__ u_t,
             const float* __restrict__ xdbl, const float* __restrict__ A_log,
             float* __restrict__ chS, float* __restrict__ chB)
{
    __shared__ float Bsh[8][CLEN];
    const int b = blockIdx.x >> 8;
    const int c = blockIdx.x & 255;
    const int d = threadIdx.x;
    const int l0 = c * CLEN;
    if (threadIdx.x < 128) {
        int i = threadIdx.x >> 3, n = threadIdx.x & 7;
        Bsh[n][i] = xdbl[((size_t)b * 4096 + l0 + i) * 48 + 32 + n];
    }
    float a[8];
#pragma unroll
    for (int n = 0; n < 8; ++n) a[n] = -__expf(A_log[d * 8 + n]);
    float h[8];
#pragma unroll
    for (int n = 0; n < 8; ++n) h[n] = 0.0f;
    float S = 0.0f;
    __syncthreads();
    const float* dp = delta_t + ((size_t)b * 4096 + l0) * 256 + d;
    const float* up = u_t     + ((size_t)b * 4096 + l0) * 256 + d;
    for (int i = 0; i < CLEN; ++i) {
        float dlt = dp[(size_t)i * 256];
        float u   = up[(size_t)i * 256];
        float du  = dlt * u;
        S += dlt;
#pragma unroll
        for (int n = 0; n < 8; ++n) {
            float dA = __expf(dlt * a[n]);
            h[n] = dA * h[n] + du * Bsh[n][i];
        }
    }
    chS[((size_t)b * NCHUNK + c) * 256 + d] = S;
#pragma unroll
    for (int n = 0; n < 8; ++n)
        chB[(((size_t)b * NCHUNK + c) * 8 + n) * 256 + d] = h[n];
}

// per (b,n): chain over 256 chunks, loads batched 16-ahead.
__global__ __launch_bounds__(256)
void k_scan2(const float* __restrict__ chS, const float* __restrict__ chB,
             const float* __restrict__ A_log, float* __restrict__ hinit)
{
    const int b = blockIdx.x >> 3;
    const int n = blockIdx.x & 7;
    const int d = threadIdx.x;
    const float a = -__expf(A_log[d * 8 + n]);
    float h = 0.0f;
    for (int cb = 0; cb < NCHUNK; cb += 16) {
        float S[16], Bc[16];
#pragma unroll
        for (int j = 0; j < 16; ++j) {
            S[j]  = chS[((size_t)b * NCHUNK + cb + j) * 256 + d];
            Bc[j] = chB[(((size_t)b * NCHUNK + cb + j) * 8 + n) * 256 + d];
        }
#pragma unroll
        for (int j = 0; j < 16; ++j) {
            hinit[(((size_t)b * NCHUNK + cb + j) * 8 + n) * 256 + d] = h;
            h = __expf(a * S[j]) * h + Bc[j];
        }
    }
}

__global__ __launch_bounds__(256)
void k_scan3(const float* __restrict__ delta_t, const float* __restrict__ u_t,
             const float* __restrict__ xdbl, const float* __restrict__ A_log,
             const float* __restrict__ Dp, const float* __restrict__ hinit,
             _Float16* __restrict__ yb)
{
    __shared__ float Bsh[8][CLEN];
    __shared__ float Csh[8][CLEN];
    const int b = blockIdx.x >> 8;
    const int c = blockIdx.x & 255;
    const int d = threadIdx.x;
    const int l0 = c * CLEN;
    {
        int s = threadIdx.x;
        if (s < 128) {
            int i = s >> 3, n = s & 7;
            Bsh[n][i] = xdbl[((size_t)b * 4096 + l0 + i) * 48 + 32 + n];
        } else {
            int s2 = s - 128;
            int i = s2 >> 3, n = s2 & 7;
            Csh[n][i] = xdbl[((size_t)b * 4096 + l0 + i) * 48 + 40 + n];
        }
    }
    float a[8], h[8];
#pragma unroll
    for (int n = 0; n < 8; ++n) {
        a[n] = -__expf(A_log[d * 8 + n]);
        h[n] = hinit[(((size_t)b * NCHUNK + c) * 8 + n) * 256 + d];
    }
    const float Dd = Dp[d];
    __syncthreads();
    const float* dp = delta_t + ((size_t)b * 4096 + l0) * 256 + d;
    const float* up = u_t     + ((size_t)b * 4096 + l0) * 256 + d;
    for (int i = 0; i < CLEN; ++i) {
        float dlt = dp[(size_t)i * 256];
        float u   = up[(size_t)i * 256];
        float du  = dlt * u;
        float y   = u * Dd;
#pragma unroll
        for (int n = 0; n < 8; ++n) {
            float dA = __expf(dlt * a[n]);
            h[n] = dA * h[n] + du * Bsh[n][i];
            y += h[n] * Csh[n][i];
        }
        int l = l0 + i;
        size_t oidx = (b < 2) ? ((size_t)b * 4096 + l) * 1024 + d
                              : ((size_t)(b - 2) * 4096 + (4095 - l)) * 1024 + 512 + d;
        yb[oidx] = (_Float16)y;
    }
}

// ============================================================================
extern "C" void kernel_launch(void* const* d_in, const int* in_sizes, int n_in,
                              void* d_out, int out_size, void* d_ws, size_t ws_size,
                              hipStream_t stream)
{
    const float* hs    = (const float*)d_in[0];   // (2,4096,512)
    const float* w_in  = (const float*)d_in[1];   // (1024,512)
    const float* w_xp  = (const float*)d_in[2];   // (48,256)
    const float* w_dt  = (const float*)d_in[3];   // (256,32)
    const float* b_dt  = (const float*)d_in[4];   // (256,)
    const float* A_log = (const float*)d_in[5];   // (256,8)
    const float* Dpar  = (const float*)d_in[6];   // (256,)
    const float* w_cx  = (const float*)d_in[7];   // (256,1,4)
    const float* w_cz  = (const float*)d_in[8];   // (256,1,4)
    const float* w_out = (const float*)d_in[9];   // (512,1024)
    float* out = (float*)d_out;                   // (2,4096,512)

    const size_t NX = (size_t)4 * 4096 * 256;       // 4,194,304 elements
    float* ws   = (float*)d_ws;
    float* x_t  = ws;                               // [4][4096][256] fp32 (dead after conv_x)
    float* u_t  = ws + NX;                          // [4][4096][256] fp32
    float* dlt  = ws + 2 * NX;                      // [4][4096][256] fp32
    float* xdbl = ws + 3 * NX;                      // [4][4096][48]
    float* chS  = xdbl + 786432;                    // [4][256][256]
    float* chB  = chS + 262144;                     // [4][256][8][256]
    float* hin  = chB + 2097152;                    // [4][256][8][256]
    float* wtT  = hin + 2097152;                    // [32][256] Wdt^T
    _Float16* z_t = (_Float16*)(wtT + 8192);        // [4][4096][256] fp16
    _Float16* hsf = z_t + NX;                       // [8192][512] fp16
    _Float16* wif = hsf + 4194304;                  // [1024][512] fp16
    _Float16* wof = wif + 524288;                   // [512][1024] fp16
    // alias (stream order makes this safe): ybuf fp16 over dead x_t (exact fit)
    _Float16* ybf = (_Float16*)x_t;                 // [2][4096][1024] fp16

    k_cast_all     <<<5152,  256, 0, stream>>>(hs, hsf, w_in, wif, w_out, wof, w_dt, wtT);
    k_in_proj_mfma <<<1024,  256, 0, stream>>>(hsf, wif, x_t, z_t);
    k_conv_x4      <<<4096,  256, 0, stream>>>(x_t, w_cx, u_t);
    k_conv_z8      <<<2048,  256, 0, stream>>>(z_t, w_cz, ybf);
    k_xproj        <<<512,   256, 0, stream>>>(u_t, w_xp, xdbl);
    k_dtproj       <<<1024,  256, 0, stream>>>(xdbl, wtT, b_dt, dlt);
    k_scan1        <<<1024,  256, 0, stream>>>(dlt, u_t, xdbl, A_log, chS, chB);
    k_scan2        <<<32,    256, 0, stream>>>(chS, chB, A_log, hin);
    k_scan3        <<<1024,  256, 0, stream>>>(dlt, u_t, xdbl, A_log, Dpar, hin, ybf);
    k_out_proj_mfma<<<512,   256, 0, stream>>>(ybf, wof, out);
}

// Round 12
// 239.886 us; speedup vs baseline: 1.0540x; 1.0540x over previous
//
#include <hip/hip_runtime.h>
#include <math.h>

// Problem constants
#define LSEQ   4096
#define DHALF  256
#define NSTATE 8
#define NCHUNK 256           // scan chunks
#define CLEN   16            // chunk length (NCHUNK*CLEN = 4096)

typedef __attribute__((ext_vector_type(8))) _Float16 half8;   // MFMA f16 A/B frag
typedef __attribute__((ext_vector_type(4))) _Float16 half4v;
typedef __attribute__((ext_vector_type(4))) float f32x4;

__device__ __forceinline__ float silu_f(float v)     { return v / (1.0f + __expf(-v)); }
__device__ __forceinline__ float softplus_f(float v) { return v > 20.0f ? v : log1pf(__expf(v)); }

// async global->LDS, 16B per lane; LDS dest = wave-uniform base + lane*16
__device__ __forceinline__ void gload16(const void* g, void* l) {
    __builtin_amdgcn_global_load_lds((const __attribute__((address_space(1))) void*)g,
                                     (__attribute__((address_space(3))) void*)l, 16, 0, 0);
}

// ============================================================================
// fp32 -> fp16 cast (3 tensors) + Wdt transpose, one launch.
// ============================================================================
__global__ __launch_bounds__(256)
void k_cast_all(const float* __restrict__ s0, _Float16* __restrict__ d0,
                const float* __restrict__ s1, _Float16* __restrict__ d1,
                const float* __restrict__ s2, _Float16* __restrict__ d2,
                const float* __restrict__ wdt, float* __restrict__ wtT)
{
    int i = blockIdx.x * 256 + threadIdx.x;
    if (i >= 1310720) {                       // seg3: transpose Wdt
        int j = i - 1310720;                  // 0..8191
        int d = j >> 5, k = j & 31;
        wtT[k * 256 + d] = wdt[j];
        return;
    }
    const float* src; _Float16* dst; int off;
    if (i < 1048576)      { src = s0; dst = d0; off = i; }
    else if (i < 1179648) { src = s1; dst = d1; off = i - 1048576; }
    else                  { src = s2; dst = d2; off = i - 1179648; }
    float4 v = ((const float4*)src)[off];
    half4v h;
    h.x = (_Float16)v.x; h.y = (_Float16)v.y; h.z = (_Float16)v.z; h.w = (_Float16)v.w;
    ((half4v*)dst)[off] = h;
}

// ============================================================================
// MFMA bt-GEMM core (C = A * B^T), fp16 single-product (fp32 accumulate).
// 128(M) x 64(N) tile / block, 4 waves each 64x32 via 4x2 16x16x32 MFMAs.
// BK=64. LDS rows 128B; 16B chunks XOR-swizzled by (row&7): conflict-free
// ds_read_b128. Swizzle applied on the per-lane GLOBAL source chunk (LDS dst
// stays uniform base + lane*16). XCD-swizzled 1D block ids: same-M0 blocks
// share bid%8 -> same XCD L2 -> A-slab fetched ~once per XCD.
// NOTE r10/r11 lessons: 128x128 / 64x128 tiles (2 blk/CU) regress; fp16
// z-stores (2B partial-line writes) regress ~17us. Keep fp32 epilogues.
// ============================================================================
#define GEMM_CORE_F16(K_, M0_, N0_)                                                     \
    const int t = threadIdx.x;                                                          \
    const int wv = t >> 6, lane = t & 63;                                               \
    const int wm = (wv & 1) * 64, wn = (wv >> 1) * 32;                                  \
    const int lm = lane & 15, q = lane >> 4;                                            \
    const int M0 = (M0_), N0 = (N0_);                                                   \
    const int lr = lane >> 3;                  /* row within 8-row group */             \
    const int cc = (lane & 7) ^ lr;            /* swizzled source chunk  */             \
    const size_t gA = (size_t)(M0 + wv * 32 + lr) * K_ + cc * 8;                        \
    const size_t gB = (size_t)(N0 + wv * 16 + lr) * K_ + cc * 8;                        \
    f32x4 acc[4][2] = {};                                                               \
    for (int kb = 0; kb < K_; kb += 64) {                                               \
        __syncthreads();                                                                \
        gload16(Af + gA + kb,               &sA[(wv * 32 +  0) * 64]);                  \
        gload16(Af + gA + (size_t)8  * K_ + kb, &sA[(wv * 32 +  8) * 64]);              \
        gload16(Af + gA + (size_t)16 * K_ + kb, &sA[(wv * 32 + 16) * 64]);              \
        gload16(Af + gA + (size_t)24 * K_ + kb, &sA[(wv * 32 + 24) * 64]);              \
        gload16(Bf + gB + kb,               &sB[(wv * 16 +  0) * 64]);                  \
        gload16(Bf + gB + (size_t)8  * K_ + kb, &sB[(wv * 16 +  8) * 64]);              \
        __syncthreads();                                                                \
        _Pragma("unroll")                                                               \
        for (int kk = 0; kk < 2; ++kk) {                                                \
            const int cpos = (((kk << 2) + q) ^ (lm & 7)) * 8;                          \
            half8 a[4], b[2];                                                           \
            _Pragma("unroll")                                                           \
            for (int i = 0; i < 4; ++i)                                                 \
                a[i] = *(const half8*)&sA[(wm + i * 16 + lm) * 64 + cpos];              \
            _Pragma("unroll")                                                           \
            for (int j = 0; j < 2; ++j)                                                 \
                b[j] = *(const half8*)&sB[(wn + j * 16 + lm) * 64 + cpos];              \
            _Pragma("unroll")                                                           \
            for (int i = 0; i < 4; ++i)                                                 \
                _Pragma("unroll")                                                       \
                for (int j = 0; j < 2; ++j)                                             \
                    acc[i][j] = __builtin_amdgcn_mfma_f32_16x16x32_f16(a[i], b[j], acc[i][j], 0, 0, 0); \
        }                                                                               \
    }

// in_proj: M=8192 (b,l), N=1024 (e), K=512. Epilogue scatter folds direction
// split + reverse, all fp32 (r9-proven). 1D grid 1024, XCD-swizzled.
__global__ __launch_bounds__(256)
void k_in_proj_mfma(const _Float16* __restrict__ Af, const _Float16* __restrict__ Bf,
                    float* __restrict__ x_t, float* __restrict__ z_t)
{
    __shared__ _Float16 sA[128 * 64], sB[64 * 64];
    GEMM_CORE_F16(512, (int)(blockIdx.x & 63) * 128, (int)(blockIdx.x >> 6) * 64)
    const int region = N0 >> 8;               // 0..3 uniform per block
    const int eobase = (N0 & 255) + wn;
    float* base = ((region & 1) == 0) ? x_t : z_t;
#pragma unroll
    for (int i = 0; i < 4; ++i) {
#pragma unroll
        for (int r = 0; r < 4; ++r) {
            int m = M0 + wm + i * 16 + q * 4 + r;
            int b = m >> 12, l = m & 4095;
            size_t rowoff = (region < 2)
                ? ((size_t)b * 4096 + l) * 256
                : ((size_t)(b + 2) * 4096 + (4095 - l)) * 256;
#pragma unroll
            for (int j = 0; j < 2; ++j)
                base[rowoff + eobase + j * 16 + lm] = acc[i][j][r];
        }
    }
}

// out_proj: M=8192 (b,l), N=512 (o), K=1024. 1D grid 512; by=bid&63, bx=bid>>6.
__global__ __launch_bounds__(256)
void k_out_proj_mfma(const _Float16* __restrict__ Af, const _Float16* __restrict__ Bf,
                     float* __restrict__ out)
{
    __shared__ _Float16 sA[128 * 64], sB[64 * 64];
    GEMM_CORE_F16(1024, (int)(blockIdx.x & 63) * 128, (int)(blockIdx.x >> 6) * 64)
#pragma unroll
    for (int i = 0; i < 4; ++i) {
#pragma unroll
        for (int r = 0; r < 4; ++r) {
            size_t m = (size_t)(M0 + wm + i * 16 + q * 4 + r);
#pragma unroll
            for (int j = 0; j < 2; ++j)
                out[m * 512 + N0 + wn + j * 16 + lm] = acc[i][j][r];
        }
    }
}

// ============================================================================
// Fused convs (independent ops, one launch): blocks 0..4095 = conv_x
// (dilated-8 causal dw conv + SiLU, x_t->u_t fp32); blocks 4096..8191 =
// conv_z (dilation-1 + SiLU, z_t -> ybuf z-channels fp16, direction
// un-reversal folded in). Block-uniform branch; bodies identical to r9.
// ============================================================================
__global__ __launch_bounds__(256)
void k_convs(const float* __restrict__ x_t, const float* __restrict__ wx,
             float* __restrict__ u_t,
             const float* __restrict__ z_t, const float* __restrict__ wz,
             _Float16* __restrict__ yb)
{
    if (blockIdx.x < 4096) {
        int idx = blockIdx.x * 256 + threadIdx.x;
        int b = idx >> 18, rem = idx & 262143;
        int l = rem >> 6, d0 = (rem & 63) * 4;
        const float* base = x_t + (size_t)b * 4096 * 256 + d0;
        float4 wv0 = *(const float4*)(wx + (d0 + 0) * 4);
        float4 wv1 = *(const float4*)(wx + (d0 + 1) * 4);
        float4 wv2 = *(const float4*)(wx + (d0 + 2) * 4);
        float4 wv3 = *(const float4*)(wx + (d0 + 3) * 4);
        float4 tp = *(const float4*)(base + (size_t)l * 256);
        float4 a = make_float4(wv0.w * tp.x, wv1.w * tp.y, wv2.w * tp.z, wv3.w * tp.w);
        if (l >= 8) {
            tp = *(const float4*)(base + (size_t)(l - 8) * 256);
            a.x += wv0.z * tp.x; a.y += wv1.z * tp.y; a.z += wv2.z * tp.z; a.w += wv3.z * tp.w;
        }
        if (l >= 16) {
            tp = *(const float4*)(base + (size_t)(l - 16) * 256);
            a.x += wv0.y * tp.x; a.y += wv1.y * tp.y; a.z += wv2.y * tp.z; a.w += wv3.y * tp.w;
        }
        if (l >= 24) {
            tp = *(const float4*)(base + (size_t)(l - 24) * 256);
            a.x += wv0.x * tp.x; a.y += wv1.x * tp.y; a.z += wv2.x * tp.z; a.w += wv3.x * tp.w;
        }
        float4 o = make_float4(silu_f(a.x), silu_f(a.y), silu_f(a.z), silu_f(a.w));
        *(float4*)(u_t + ((size_t)b * 4096 + l) * 256 + d0) = o;
    } else {
        int idx = (blockIdx.x - 4096) * 256 + threadIdx.x;
        int b = idx >> 18, rem = idx & 262143;
        int l = rem >> 6, d0 = (rem & 63) * 4;
        const float* base = z_t + (size_t)b * 4096 * 256 + d0;
        float4 wv0 = *(const float4*)(wz + (d0 + 0) * 4);
        float4 wv1 = *(const float4*)(wz + (d0 + 1) * 4);
        float4 wv2 = *(const float4*)(wz + (d0 + 2) * 4);
        float4 wv3 = *(const float4*)(wz + (d0 + 3) * 4);
        float4 tp = *(const float4*)(base + (size_t)l * 256);
        float4 a = make_float4(wv0.w * tp.x, wv1.w * tp.y, wv2.w * tp.z, wv3.w * tp.w);
        if (l >= 1) {
            tp = *(const float4*)(base + (size_t)(l - 1) * 256);
            a.x += wv0.z * tp.x; a.y += wv1.z * tp.y; a.z += wv2.z * tp.z; a.w += wv3.z * tp.w;
        }
        if (l >= 2) {
            tp = *(const float4*)(base + (size_t)(l - 2) * 256);
            a.x += wv0.y * tp.x; a.y += wv1.y * tp.y; a.z += wv2.y * tp.z; a.w += wv3.y * tp.w;
        }
        if (l >= 3) {
            tp = *(const float4*)(base + (size_t)(l - 3) * 256);
            a.x += wv0.x * tp.x; a.y += wv1.x * tp.y; a.z += wv2.x * tp.z; a.w += wv3.x * tp.w;
        }
        size_t oidx = (b < 2) ? ((size_t)b * 4096 + l) * 1024 + 256 + d0
                              : ((size_t)(b - 2) * 4096 + (4095 - l)) * 1024 + 768 + d0;
        half4v h;
        h.x = (_Float16)silu_f(a.x); h.y = (_Float16)silu_f(a.y);
        h.z = (_Float16)silu_f(a.z); h.w = (_Float16)silu_f(a.w);
        *(half4v*)(yb + oidx) = h;
    }
}

// ============================================================================
// x_proj: xdbl[m][e] = sum_d u_t[m][d] * Wx[e][d];  M=16384, N=48, K=256
// 512 blocks of 32 rows.
// ============================================================================
__global__ __launch_bounds__(256)
void k_xproj(const float* __restrict__ U, const float* __restrict__ W,
             float* __restrict__ xdbl)
{
    __shared__ float Xs[32][260];
    __shared__ float Ws[48][68];
    const int t  = threadIdx.x;
    const int m0 = blockIdx.x * 32;
#pragma unroll
    for (int it = 0; it < 8; ++it) {       // 32x256 = 2048 float4
        int idx = t + 256 * it;
        int row = idx >> 6, c = (idx & 63) * 4;
        *(float4*)&Xs[row][c] = *(const float4*)(U + (size_t)(m0 + row) * 256 + c);
    }
    const int r  = t >> 3;                 // 0..31
    const int j0 = (t & 7) * 6;            // 0..42
    float acc[6] = {};
    for (int kb = 0; kb < 256; kb += 64) {
        __syncthreads();
#pragma unroll
        for (int it = 0; it < 3; ++it) {   // 48x64 = 768 float4
            int idx = t + 256 * it;
            int wr = idx >> 4, wc = (idx & 15) * 4;
            *(float4*)&Ws[wr][wc] = *(const float4*)(W + (size_t)wr * 256 + kb + wc);
        }
        __syncthreads();
#pragma unroll
        for (int k4 = 0; k4 < 16; ++k4) {
            float4 x = *(const float4*)&Xs[r][kb + k4 * 4];
#pragma unroll
            for (int jj = 0; jj < 6; ++jj) {
                float4 wv = *(const float4*)&Ws[j0 + jj][k4 * 4];
                acc[jj] = fmaf(x.x, wv.x, acc[jj]);
                acc[jj] = fmaf(x.y, wv.y, acc[jj]);
                acc[jj] = fmaf(x.z, wv.z, acc[jj]);
                acc[jj] = fmaf(x.w, wv.w, acc[jj]);
            }
        }
    }
    float* dst = xdbl + (size_t)(m0 + r) * 48 + j0;
#pragma unroll
    for (int jj = 0; jj < 6; ++jj) dst[jj] = acc[jj];
}

// ============================================================================
// dt_proj + softplus. Thread = channel d; W from TRANSPOSED WT[32][256]
// (coalesced wave-load). 1024 blocks x 16 m-rows.
// ============================================================================
__global__ __launch_bounds__(256)
void k_dtproj(const float* __restrict__ xdbl, const float* __restrict__ WT,
              const float* __restrict__ bdt, float* __restrict__ delta_t)
{
    __shared__ float Xs[16][32];
    const int t  = threadIdx.x;            // d = t
    const int m0 = blockIdx.x * 16;
    if (t < 128) {                         // 16x32 floats = 128 float4
        int r = t >> 3, c = (t & 7) * 4;
        *(float4*)&Xs[r][c] = *(const float4*)(xdbl + (size_t)(m0 + r) * 48 + c);
    }
    float w[32];
#pragma unroll
    for (int k = 0; k < 32; ++k) w[k] = WT[k * 256 + t];
    const float bias = bdt[t];
    __syncthreads();
#pragma unroll
    for (int m = 0; m < 16; ++m) {
        const float4* xr = (const float4*)&Xs[m][0];
        float acc = bias;
#pragma unroll
        for (int j = 0; j < 8; ++j) {
            float4 xv = xr[j];
            acc = fmaf(xv.x, w[4*j+0], acc);
            acc = fmaf(xv.y, w[4*j+1], acc);
            acc = fmaf(xv.z, w[4*j+2], acc);
            acc = fmaf(xv.w, w[4*j+3], acc);
        }
        delta_t[(size_t)(m0 + m) * 256 + t] = softplus_f(acc);
    }
}

// ============================================================================
// Selective scan, chunked (NCHUNK=256 chunks x CLEN=16 steps). All fp32.
// Staging guards: 128 writers into [8][16] — in bounds.
// ============================================================================
__global__ __launch_bounds__(256)
void k_scan1(const float* __restrict__ delta_t, const float* __restrict__ u_t,
             const float* __restrict__ xdbl, const float* __restrict__ A_log,
             float* __restrict__ chS, float* __restrict__ chB)
{
    __shared__ float Bsh[8][CLEN];
    const int b = blockIdx.x >> 8;
    const int c = blockIdx.x & 255;
    const int d = threadIdx.x;
    const int l0 = c * CLEN;
    if (threadIdx.x < 128) {
        int i = threadIdx.x >> 3, n = threadIdx.x & 7;
        Bsh[n][i] = xdbl[((size_t)b * 4096 + l0 + i) * 48 + 32 + n];
    }
    float a[8];
#pragma unroll
    for (int n = 0; n < 8; ++n) a[n] = -__expf(A_log[d * 8 + n]);
    float h[8];
#pragma unroll
    for (int n = 0; n < 8; ++n) h[n] = 0.0f;
    float S = 0.0f;
    __syncthreads();
    const float* dp = delta_t + ((size_t)b * 4096 + l0) * 256 + d;
    const float* up = u_t     + ((size_t)b * 4096 + l0) * 256 + d;
    for (int i = 0; i < CLEN; ++i) {
        float dlt = dp[(size_t)i * 256];
        float u   = up[(size_t)i * 256];
        float du  = dlt * u;
        S += dlt;
#pragma unroll
        for (int n = 0; n < 8; ++n) {
            float dA = __expf(dlt * a[n]);
            h[n] = dA * h[n] + du * Bsh[n][i];
        }
    }
    chS[((size_t)b * NCHUNK + c) * 256 + d] = S;
#pragma unroll
    for (int n = 0; n < 8; ++n)
        chB[(((size_t)b * NCHUNK + c) * 8 + n) * 256 + d] = h[n];
}

// per (b,n): chain over 256 chunks, loads batched 16-ahead.
__global__ __launch_bounds__(256)
void k_scan2(const float* __restrict__ chS, const float* __restrict__ chB,
             const float* __restrict__ A_log, float* __restrict__ hinit)
{
    const int b = blockIdx.x >> 3;
    const int n = blockIdx.x & 7;
    const int d = threadIdx.x;
    const float a = -__expf(A_log[d * 8 + n]);
    float h = 0.0f;
    for (int cb = 0; cb < NCHUNK; cb += 16) {
        float S[16], Bc[16];
#pragma unroll
        for (int j = 0; j < 16; ++j) {
            S[j]  = chS[((size_t)b * NCHUNK + cb + j) * 256 + d];
            Bc[j] = chB[(((size_t)b * NCHUNK + cb + j) * 8 + n) * 256 + d];
        }
#pragma unroll
        for (int j = 0; j < 16; ++j) {
            hinit[(((size_t)b * NCHUNK + cb + j) * 8 + n) * 256 + d] = h;
            h = __expf(a * S[j]) * h + Bc[j];
        }
    }
}

__global__ __launch_bounds__(256)
void k_scan3(const float* __restrict__ delta_t, const float* __restrict__ u_t,
             const float* __restrict__ xdbl, const float* __restrict__ A_log,
             const float* __restrict__ Dp, const float* __restrict__ hinit,
             _Float16* __restrict__ yb)
{
    __shared__ float Bsh[8][CLEN];
    __shared__ float Csh[8][CLEN];
    const int b = blockIdx.x >> 8;
    const int c = blockIdx.x & 255;
    const int d = threadIdx.x;
    const int l0 = c * CLEN;
    {
        int s = threadIdx.x;
        if (s < 128) {
            int i = s >> 3, n = s & 7;
            Bsh[n][i] = xdbl[((size_t)b * 4096 + l0 + i) * 48 + 32 + n];
        } else {
            int s2 = s - 128;
            int i = s2 >> 3, n = s2 & 7;
            Csh[n][i] = xdbl[((size_t)b * 4096 + l0 + i) * 48 + 40 + n];
        }
    }
    float a[8], h[8];
#pragma unroll
    for (int n = 0; n < 8; ++n) {
        a[n] = -__expf(A_log[d * 8 + n]);
        h[n] = hinit[(((size_t)b * NCHUNK + c) * 8 + n) * 256 + d];
    }
    const float Dd = Dp[d];
    __syncthreads();
    const float* dp = delta_t + ((size_t)b * 4096 + l0) * 256 + d;
    const float* up = u_t     + ((size_t)b * 4096 + l0) * 256 + d;
    for (int i = 0; i < CLEN; ++i) {
        float dlt = dp[(size_t)i * 256];
        float u   = up[(size_t)i * 256];
        float du  = dlt * u;
        float y   = u * Dd;
#pragma unroll
        for (int n = 0; n < 8; ++n) {
            float dA = __expf(dlt * a[n]);
            h[n] = dA * h[n] + du * Bsh[n][i];
            y += h[n] * Csh[n][i];
        }
        int l = l0 + i;
        size_t oidx = (b < 2) ? ((size_t)b * 4096 + l) * 1024 + d
                              : ((size_t)(b - 2) * 4096 + (4095 - l)) * 1024 + 512 + d;
        yb[oidx] = (_Float16)y;
    }
}

// ============================================================================
extern "C" void kernel_launch(void* const* d_in, const int* in_sizes, int n_in,
                              void* d_out, int out_size, void* d_ws, size_t ws_size,
                              hipStream_t stream)
{
    const float* hs    = (const float*)d_in[0];   // (2,4096,512)
    const float* w_in  = (const float*)d_in[1];   // (1024,512)
    const float* w_xp  = (const float*)d_in[2];   // (48,256)
    const float* w_dt  = (const float*)d_in[3];   // (256,32)
    const float* b_dt  = (const float*)d_in[4];   // (256,)
    const float* A_log = (const float*)d_in[5];   // (256,8)
    const float* Dpar  = (const float*)d_in[6];   // (256,)
    const float* w_cx  = (const float*)d_in[7];   // (256,1,4)
    const float* w_cz  = (const float*)d_in[8];   // (256,1,4)
    const float* w_out = (const float*)d_in[9];   // (512,1024)
    float* out = (float*)d_out;                   // (2,4096,512)

    const size_t NX = (size_t)4 * 4096 * 256;       // 4,194,304 elements
    float* ws   = (float*)d_ws;
    float* x_t  = ws;                               // [4][4096][256] fp32 (dead after conv_x)
    float* z_t  = ws + NX;                          // [4][4096][256] fp32
    float* u_t  = ws + 2 * NX;                      // [4][4096][256] fp32
    float* dlt  = ws + 3 * NX;                      // [4][4096][256] fp32
    float* xdbl = ws + 4 * NX;                      // [4][4096][48]
    float* chS  = xdbl + 786432;                    // [4][256][256]
    float* chB  = chS + 262144;                     // [4][256][8][256]
    float* hin  = chB + 2097152;                    // [4][256][8][256]
    float* wtT  = hin + 2097152;                    // [32][256] Wdt^T
    _Float16* hsf = (_Float16*)(wtT + 8192);        // [8192][512] fp16
    _Float16* wif = hsf + 4194304;                  // [1024][512] fp16
    _Float16* wof = wif + 524288;                   // [512][1024] fp16
    // alias (stream order makes this safe): ybuf fp16 over dead x_t (exact fit)
    _Float16* ybf = (_Float16*)x_t;                 // [2][4096][1024] fp16

    k_cast_all     <<<5152,  256, 0, stream>>>(hs, hsf, w_in, wif, w_out, wof, w_dt, wtT);
    k_in_proj_mfma <<<1024,  256, 0, stream>>>(hsf, wif, x_t, z_t);
    k_convs        <<<8192,  256, 0, stream>>>(x_t, w_cx, u_t, z_t, w_cz, ybf);
    k_xproj        <<<512,   256, 0, stream>>>(u_t, w_xp, xdbl);
    k_dtproj       <<<1024,  256, 0, stream>>>(xdbl, wtT, b_dt, dlt);
    k_scan1        <<<1024,  256, 0, stream>>>(dlt, u_t, xdbl, A_log, chS, chB);
    k_scan2        <<<32,    256, 0, stream>>>(chS, chB, A_log, hin);
    k_scan3        <<<1024,  256, 0, stream>>>(dlt, u_t, xdbl, A_log, Dpar, hin, ybf);
    k_out_proj_mfma<<<512,   256, 0, stream>>>(ybf, wof, out);
}